// Round 3
// baseline (450.932 us; speedup 1.0000x reference)
//
#include <hip/hip_runtime.h>
#include <hip/hip_bf16.h>
#include <math.h>

#define NEG_SLOPE_F 0.2f

static __device__ __forceinline__ float lrelu(float x) {
    return x > 0.f ? x : NEG_SLOPE_F * x;
}

template<typename T> __device__ __forceinline__ float toF(T v);
template<> __device__ __forceinline__ float toF<float>(float v) { return v; }
template<> __device__ __forceinline__ float toF<__hip_bfloat16>(__hip_bfloat16 v) { return __bfloat162float(v); }
template<typename T> __device__ __forceinline__ T toT(float f);
template<> __device__ __forceinline__ float toT<float>(float f) { return f; }
template<> __device__ __forceinline__ __hip_bfloat16 toT<__hip_bfloat16>(float f) { return __float2bfloat16(f); }

// ---------------- utility ----------------
__global__ void k_zero(int* __restrict__ p, int n) {
    int i = blockIdx.x * blockDim.x + threadIdx.x;
    if (i < n) p[i] = 0;
}

// ---------------- CSR build ----------------
// edge_index arrives as int32 (harness converts integer inputs to int32),
// flat [2][E]: src = ei[t], dst = ei[E + t].
__global__ void k_hist(const int* __restrict__ ei, int E, int N, int* __restrict__ deg) {
    int t = blockIdx.x * blockDim.x + threadIdx.x;
    int total = E + N;
    if (t >= total) return;
    int d = (t < E) ? ei[E + t] : (t - E);   // dst (self-loop for t>=E)
    if (d >= 0 && d < N) atomicAdd(&deg[d], 1);
}

__global__ __launch_bounds__(1024) void k_scan1(const int* __restrict__ deg, int N,
                                                int* __restrict__ excl, int* __restrict__ bsum) {
    __shared__ int sm[1024];
    int i = blockIdx.x * 1024 + threadIdx.x;
    int v = (i < N) ? deg[i] : 0;
    sm[threadIdx.x] = v;
    __syncthreads();
    int acc = v;
    for (int off = 1; off < 1024; off <<= 1) {
        int other = (threadIdx.x >= (unsigned)off) ? sm[threadIdx.x - off] : 0;
        __syncthreads();
        acc += other;
        sm[threadIdx.x] = acc;
        __syncthreads();
    }
    if (i < N) excl[i] = acc - v;          // exclusive within block
    if (threadIdx.x == 1023) bsum[blockIdx.x] = acc;
}

__global__ void k_scan2(int* __restrict__ bsum, int nb) {
    if (blockIdx.x == 0 && threadIdx.x == 0) {
        int run = 0;
        for (int i = 0; i < nb; ++i) { int v = bsum[i]; bsum[i] = run; run += v; }
    }
}

__global__ void k_scan3(const int* __restrict__ excl, const int* __restrict__ bsum, int N, int total,
                        int* __restrict__ rowptr, int* __restrict__ cursor) {
    int i = blockIdx.x * blockDim.x + threadIdx.x;
    if (i < N) {
        int v = excl[i] + bsum[i >> 10];
        rowptr[i] = v;
        cursor[i] = v;
    }
    if (i == 0) rowptr[N] = total;
}

__global__ void k_fill(const int* __restrict__ ei, int E, int N,
                       int* __restrict__ cursor, int* __restrict__ csrc, int total) {
    int t = blockIdx.x * blockDim.x + threadIdx.x;
    if (t >= E + N) return;
    int s, d;
    if (t < E) { s = ei[t]; d = ei[E + t]; }
    else       { s = t - E; d = s; }
    if (d < 0 || d >= N || s < 0 || s >= N) return;
    int pos = atomicAdd(&cursor[d], 1);
    if (pos >= 0 && pos < total) csrc[pos] = s;
}

// ---------------- GEMM: h[N][128] = x[N][128] @ W[128][128] ----------------
template<typename T>
__global__ __launch_bounds__(256) void k_gemm(const float* __restrict__ x, const float* __restrict__ W,
                                              T* __restrict__ h, int M) {
    __shared__ float xs[32][64];    // [k][row]
    __shared__ float wsm[32][132];  // [k][col], padded row
    int tid = threadIdx.x;
    int ct = tid & 15;              // 16 col groups x 8 cols
    int rt = tid >> 4;              // 16 row groups x 4 rows
    int row0 = blockIdx.x * 64;

    float acc[4][8];
#pragma unroll
    for (int i = 0; i < 4; ++i)
#pragma unroll
        for (int j = 0; j < 8; ++j) acc[i][j] = 0.f;

    for (int k0 = 0; k0 < 128; k0 += 32) {
#pragma unroll
        for (int rr = 0; rr < 64; rr += 32) {
            int r = rr + (tid >> 3);
            int f4 = tid & 7;
            float4 v = make_float4(0.f, 0.f, 0.f, 0.f);
            int gr = row0 + r;
            if (gr < M) v = *(const float4*)&x[(size_t)gr * 128 + k0 + f4 * 4];
            xs[f4 * 4 + 0][r] = v.x;
            xs[f4 * 4 + 1][r] = v.y;
            xs[f4 * 4 + 2][r] = v.z;
            xs[f4 * 4 + 3][r] = v.w;
        }
#pragma unroll
        for (int j = 0; j < 4; ++j) {
            int idx = tid + j * 256;        // float4 index in [0,1024)
            int kr = idx >> 5;
            int c4 = idx & 31;
            float4 v = *(const float4*)&W[(size_t)(k0 + kr) * 128 + c4 * 4];
            *(float4*)&wsm[kr][c4 * 4] = v;
        }
        __syncthreads();
#pragma unroll
        for (int kk = 0; kk < 32; ++kk) {
            float4 a = *(const float4*)&xs[kk][rt * 4];
            float4 b0 = *(const float4*)&wsm[kk][ct * 8];
            float4 b1 = *(const float4*)&wsm[kk][ct * 8 + 4];
            float av[4] = {a.x, a.y, a.z, a.w};
            float bv[8] = {b0.x, b0.y, b0.z, b0.w, b1.x, b1.y, b1.z, b1.w};
#pragma unroll
            for (int i = 0; i < 4; ++i)
#pragma unroll
                for (int j = 0; j < 8; ++j) acc[i][j] = fmaf(av[i], bv[j], acc[i][j]);
        }
        __syncthreads();
    }
#pragma unroll
    for (int i = 0; i < 4; ++i) {
        int gr = row0 + rt * 4 + i;
        if (gr < M) {
#pragma unroll
            for (int j = 0; j < 8; ++j)
                h[(size_t)gr * 128 + ct * 8 + j] = toT<T>(acc[i][j]);
        }
    }
}

// ---------------- per-node attention halves: a_src/a_dst [N][4] ----------------
template<typename T>
__global__ void k_att(const T* __restrict__ h, const float* __restrict__ att_s,
                      const float* __restrict__ att_d, float* __restrict__ as,
                      float* __restrict__ ad, int N) {
    int t = blockIdx.x * blockDim.x + threadIdx.x;   // blockDim = 256
    int n = t >> 7;
    int j = t & 127;
    if (n >= N) return;
    float v = toF(h[(size_t)n * 128 + j]);
    float ps = v * att_s[j];
    float pd = v * att_d[j];
#pragma unroll
    for (int off = 16; off >= 1; off >>= 1) {
        ps += __shfl_xor(ps, off, 64);
        pd += __shfl_xor(pd, off, 64);
    }
    if ((j & 31) == 0) {
        int hh = j >> 5;
        as[n * 4 + hh] = ps;
        ad[n * 4 + hh] = pd;
    }
}

// ---------------- per-dst softmax + aggregate ----------------
#define AGG_CAP 128
template<typename T>
__global__ __launch_bounds__(128) void k_agg(const T* __restrict__ h, const float* __restrict__ as,
                                             const float* __restrict__ ad, const int* __restrict__ rowptr,
                                             const int* __restrict__ csrc, const float* __restrict__ bias,
                                             float* __restrict__ out, int N) {
    __shared__ float wlds[AGG_CAP][4];
    __shared__ int srcs[AGG_CAP];
    __shared__ float mmax[4], minv[4];

    int n = blockIdx.x;
    int tid = threadIdx.x;
    int o0 = rowptr[n], o1 = rowptr[n + 1];
    int deg = o1 - o0;

    float4 adn = *(const float4*)&ad[n * 4];
    float adh[4] = {adn.x, adn.y, adn.z, adn.w};

    if (tid < 64) {
        float mx[4] = {-1e30f, -1e30f, -1e30f, -1e30f};
        for (int i = tid; i < deg; i += 64) {
            int s = csrc[o0 + i];
            float4 a = *(const float4*)&as[s * 4];
            float e0 = lrelu(a.x + adh[0]);
            float e1 = lrelu(a.y + adh[1]);
            float e2 = lrelu(a.z + adh[2]);
            float e3 = lrelu(a.w + adh[3]);
            if (i < AGG_CAP) {
                srcs[i] = s;
                wlds[i][0] = e0; wlds[i][1] = e1; wlds[i][2] = e2; wlds[i][3] = e3;
            }
            mx[0] = fmaxf(mx[0], e0); mx[1] = fmaxf(mx[1], e1);
            mx[2] = fmaxf(mx[2], e2); mx[3] = fmaxf(mx[3], e3);
        }
#pragma unroll
        for (int off = 32; off >= 1; off >>= 1) {
#pragma unroll
            for (int q = 0; q < 4; ++q) mx[q] = fmaxf(mx[q], __shfl_xor(mx[q], off, 64));
        }
        float sm[4] = {0.f, 0.f, 0.f, 0.f};
        for (int i = tid; i < deg; i += 64) {
            float e[4];
            if (i < AGG_CAP) {
                e[0] = wlds[i][0]; e[1] = wlds[i][1]; e[2] = wlds[i][2]; e[3] = wlds[i][3];
            } else {
                int s = csrc[o0 + i];
                float4 a = *(const float4*)&as[s * 4];
                e[0] = lrelu(a.x + adh[0]); e[1] = lrelu(a.y + adh[1]);
                e[2] = lrelu(a.z + adh[2]); e[3] = lrelu(a.w + adh[3]);
            }
#pragma unroll
            for (int q = 0; q < 4; ++q) {
                float ex = expf(e[q] - mx[q]);
                sm[q] += ex;
                if (i < AGG_CAP) wlds[i][q] = ex;
            }
        }
#pragma unroll
        for (int off = 32; off >= 1; off >>= 1) {
#pragma unroll
            for (int q = 0; q < 4; ++q) sm[q] += __shfl_xor(sm[q], off, 64);
        }
        if (tid == 0) {
#pragma unroll
            for (int q = 0; q < 4; ++q) {
                mmax[q] = mx[q];
                minv[q] = 1.f / (sm[q] + 1e-16f);
            }
        }
    }
    __syncthreads();

    int hh = tid >> 5;               // head (0..3); tid = hh*32 + c
    float mxh = mmax[hh];
    float invh = minv[hh];
    float adhh = adh[hh];
    float acc = 0.f;
    for (int i = 0; i < deg; ++i) {
        int s; float w;
        if (i < AGG_CAP) {
            s = srcs[i];
            w = wlds[i][hh];
        } else {
            s = csrc[o0 + i];
            float e = lrelu(as[s * 4 + hh] + adhh);
            w = expf(e - mxh);
        }
        acc = fmaf(w, toF(h[(size_t)s * 128 + tid]), acc);
    }
    acc *= invh;
    float r = acc + bias[tid];
    out[(size_t)n * 128 + tid] = r > 0.f ? r : expf(r) - 1.f;
}

// ---------------- launch ----------------
extern "C" void kernel_launch(void* const* d_in, const int* in_sizes, int n_in,
                              void* d_out, int out_size, void* d_ws, size_t ws_size,
                              hipStream_t stream) {
    const float* x     = (const float*)d_in[0];
    const int*   ei    = (const int*)d_in[1];     // int32 [2][E] flat (harness converts ints to int32)
    const float* W     = (const float*)d_in[2];
    const float* att_s = (const float*)d_in[3];
    const float* att_d = (const float*)d_in[4];
    const float* bias  = (const float*)d_in[5];
    float* out = (float*)d_out;

    int N = in_sizes[0] / 128;
    int E = in_sizes[1] / 2;
    int total = E + N;

    auto align256 = [](size_t v) { return (v + 255) & ~(size_t)255; };

    size_t fixed = align256((size_t)N * 16) * 2          // as, ad
                 + align256((size_t)N * 4) * 3           // deg, excl, cursor
                 + align256(4096)                        // bsum
                 + align256(((size_t)N + 1) * 4)         // rowptr
                 + align256((size_t)total * 4);          // csrc
    size_t needF32 = fixed + align256((size_t)N * 128 * 4);
    bool useF32 = (ws_size >= needF32);
    size_t hbytes = useF32 ? 4 : 2;

    char* wsp = (char*)d_ws;
    size_t off = 0;
    auto alloc = [&](size_t bytes) {
        char* p = wsp + off;
        off += align256(bytes);
        return p;
    };
    void*  hbuf   = alloc((size_t)N * 128 * hbytes);
    float* as     = (float*)alloc((size_t)N * 16);
    float* ad     = (float*)alloc((size_t)N * 16);
    int*   deg    = (int*)alloc((size_t)N * 4);
    int*   excl   = (int*)alloc((size_t)N * 4);
    int*   bsum   = (int*)alloc(4096);
    int*   rowptr = (int*)alloc(((size_t)N + 1) * 4);
    int*   cursor = (int*)alloc((size_t)N * 4);
    int*   csrc   = (int*)alloc((size_t)total * 4);

    int nbScan = (N + 1023) / 1024;
    int nbEdge = (total + 255) / 256;

    k_zero<<<(N + 255) / 256, 256, 0, stream>>>(deg, N);
    k_hist<<<nbEdge, 256, 0, stream>>>(ei, E, N, deg);
    k_scan1<<<nbScan, 1024, 0, stream>>>(deg, N, excl, bsum);
    k_scan2<<<1, 64, 0, stream>>>(bsum, nbScan);
    k_scan3<<<(N + 255) / 256, 256, 0, stream>>>(excl, bsum, N, total, rowptr, cursor);
    k_fill<<<nbEdge, 256, 0, stream>>>(ei, E, N, cursor, csrc, total);

    if (useF32) {
        float* h = (float*)hbuf;
        k_gemm<float><<<(N + 63) / 64, 256, 0, stream>>>(x, W, h, N);
        k_att<float><<<((size_t)N * 128 + 255) / 256, 256, 0, stream>>>(h, att_s, att_d, as, ad, N);
        k_agg<float><<<N, 128, 0, stream>>>(h, as, ad, rowptr, csrc, bias, out, N);
    } else {
        __hip_bfloat16* h = (__hip_bfloat16*)hbuf;
        k_gemm<__hip_bfloat16><<<(N + 63) / 64, 256, 0, stream>>>(x, W, h, N);
        k_att<__hip_bfloat16><<<((size_t)N * 128 + 255) / 256, 256, 0, stream>>>(h, att_s, att_d, as, ad, N);
        k_agg<__hip_bfloat16><<<N, 128, 0, stream>>>(h, as, ad, rowptr, csrc, bias, out, N);
    }
}

// Round 4
// 427.909 us; speedup vs baseline: 1.0538x; 1.0538x over previous
//
#include <hip/hip_runtime.h>
#include <math.h>

#define NEG_SLOPE_F 0.2f

static __device__ __forceinline__ float lrelu(float x) {
    return x > 0.f ? x : NEG_SLOPE_F * x;
}

// bf16 pack/unpack via bit ops (RNE; inputs are finite)
static __device__ __forceinline__ unsigned short f2bf(float f) {
    unsigned u = __float_as_uint(f);
    unsigned r = u + 0x7FFFu + ((u >> 16) & 1u);
    return (unsigned short)(r >> 16);
}
static __device__ __forceinline__ float bflo(unsigned w) { return __uint_as_float(w << 16); }
static __device__ __forceinline__ float bfhi(unsigned w) { return __uint_as_float(w & 0xFFFF0000u); }

// ---------------- utility ----------------
__global__ void k_zero(int* __restrict__ p, int n) {
    int i = blockIdx.x * blockDim.x + threadIdx.x;
    if (i < n) p[i] = 0;
}

// ---------------- CSR build ----------------
// edge_index arrives as int32 flat [2][E]: src = ei[t], dst = ei[E + t].
__global__ void k_hist(const int* __restrict__ ei, int E, int N, int* __restrict__ deg) {
    int t = blockIdx.x * blockDim.x + threadIdx.x;
    int total = E + N;
    if (t >= total) return;
    int d = (t < E) ? ei[E + t] : (t - E);
    if (d >= 0 && d < N) atomicAdd(&deg[d], 1);
}

__global__ __launch_bounds__(1024) void k_scan1(const int* __restrict__ deg, int N,
                                                int* __restrict__ excl, int* __restrict__ bsum) {
    __shared__ int sm[1024];
    int i = blockIdx.x * 1024 + threadIdx.x;
    int v = (i < N) ? deg[i] : 0;
    sm[threadIdx.x] = v;
    __syncthreads();
    int acc = v;
    for (int off = 1; off < 1024; off <<= 1) {
        int other = (threadIdx.x >= (unsigned)off) ? sm[threadIdx.x - off] : 0;
        __syncthreads();
        acc += other;
        sm[threadIdx.x] = acc;
        __syncthreads();
    }
    if (i < N) excl[i] = acc - v;
    if (threadIdx.x == 1023) bsum[blockIdx.x] = acc;
}

// parallel single-block exclusive scan over nb (<=1024) block sums
__global__ __launch_bounds__(1024) void k_scan2(int* __restrict__ bsum, int nb) {
    __shared__ int sm[1024];
    int t = threadIdx.x;
    int v = (t < nb) ? bsum[t] : 0;
    sm[t] = v;
    __syncthreads();
    int acc = v;
    for (int off = 1; off < 1024; off <<= 1) {
        int other = (t >= (unsigned)off) ? sm[t - off] : 0;
        __syncthreads();
        acc += other;
        sm[t] = acc;
        __syncthreads();
    }
    if (t < nb) bsum[t] = acc - v;   // exclusive
}

__global__ void k_scan3(const int* __restrict__ excl, const int* __restrict__ bsum, int N, int total,
                        int* __restrict__ rowptr, int* __restrict__ cursor) {
    int i = blockIdx.x * blockDim.x + threadIdx.x;
    if (i < N) {
        int v = excl[i] + bsum[i >> 10];
        rowptr[i] = v;
        cursor[i] = v;
    }
    if (i == 0) rowptr[N] = total;
}

__global__ void k_fill(const int* __restrict__ ei, int E, int N,
                       int* __restrict__ cursor, int* __restrict__ csrc, int total) {
    int t = blockIdx.x * blockDim.x + threadIdx.x;
    if (t >= E + N) return;
    int s, d;
    if (t < E) { s = ei[t]; d = ei[E + t]; }
    else       { s = t - E; d = s; }
    if (d < 0 || d >= N || s < 0 || s >= N) return;
    int pos = atomicAdd(&cursor[d], 1);
    if (pos >= 0 && pos < total) csrc[pos] = s;
}

// ---------------- GEMM + fused attention halves ----------------
// h_bf16[N][128] = bf16(x @ W); as/ad[N][4] = sum_c h*att per head (from fp32 acc)
__global__ __launch_bounds__(256) void k_gemm(const float* __restrict__ x, const float* __restrict__ W,
                                              unsigned short* __restrict__ h,
                                              const float* __restrict__ att_s, const float* __restrict__ att_d,
                                              float* __restrict__ as, float* __restrict__ ad, int M) {
    __shared__ float xs[32][64];
    __shared__ float wsm[32][132];
    int tid = threadIdx.x;
    int ct = tid & 15;              // 16 col groups x 8 cols
    int rt = tid >> 4;              // 16 row groups x 4 rows
    int row0 = blockIdx.x * 64;

    float acc[4][8];
#pragma unroll
    for (int i = 0; i < 4; ++i)
#pragma unroll
        for (int j = 0; j < 8; ++j) acc[i][j] = 0.f;

    for (int k0 = 0; k0 < 128; k0 += 32) {
#pragma unroll
        for (int rr = 0; rr < 64; rr += 32) {
            int r = rr + (tid >> 3);
            int f4 = tid & 7;
            float4 v = make_float4(0.f, 0.f, 0.f, 0.f);
            int gr = row0 + r;
            if (gr < M) v = *(const float4*)&x[(size_t)gr * 128 + k0 + f4 * 4];
            xs[f4 * 4 + 0][r] = v.x;
            xs[f4 * 4 + 1][r] = v.y;
            xs[f4 * 4 + 2][r] = v.z;
            xs[f4 * 4 + 3][r] = v.w;
        }
#pragma unroll
        for (int j = 0; j < 4; ++j) {
            int idx = tid + j * 256;
            int kr = idx >> 5;
            int c4 = idx & 31;
            float4 v = *(const float4*)&W[(size_t)(k0 + kr) * 128 + c4 * 4];
            *(float4*)&wsm[kr][c4 * 4] = v;
        }
        __syncthreads();
#pragma unroll
        for (int kk = 0; kk < 32; ++kk) {
            float4 a = *(const float4*)&xs[kk][rt * 4];
            float4 b0 = *(const float4*)&wsm[kk][ct * 8];
            float4 b1 = *(const float4*)&wsm[kk][ct * 8 + 4];
            float av[4] = {a.x, a.y, a.z, a.w};
            float bv[8] = {b0.x, b0.y, b0.z, b0.w, b1.x, b1.y, b1.z, b1.w};
#pragma unroll
            for (int i = 0; i < 4; ++i)
#pragma unroll
                for (int j = 0; j < 8; ++j) acc[i][j] = fmaf(av[i], bv[j], acc[i][j]);
        }
        __syncthreads();
    }

    // attention vector slices for this thread's 8 cols (head = ct>>2)
    float asv[8], adv[8];
#pragma unroll
    for (int j = 0; j < 8; ++j) {
        asv[j] = att_s[ct * 8 + j];
        adv[j] = att_d[ct * 8 + j];
    }

#pragma unroll
    for (int i = 0; i < 4; ++i) {
        int gr = row0 + rt * 4 + i;
        if (gr >= M) continue;
        // store bf16 row chunk (16B)
        uint4 pk;
        pk.x = (unsigned)f2bf(acc[i][0]) | ((unsigned)f2bf(acc[i][1]) << 16);
        pk.y = (unsigned)f2bf(acc[i][2]) | ((unsigned)f2bf(acc[i][3]) << 16);
        pk.z = (unsigned)f2bf(acc[i][4]) | ((unsigned)f2bf(acc[i][5]) << 16);
        pk.w = (unsigned)f2bf(acc[i][6]) | ((unsigned)f2bf(acc[i][7]) << 16);
        *(uint4*)&h[(size_t)gr * 128 + ct * 8] = pk;
        // per-head attention partials (8 cols all within head ct>>2)
        float ps = 0.f, pd = 0.f;
#pragma unroll
        for (int j = 0; j < 8; ++j) {
            ps = fmaf(acc[i][j], asv[j], ps);
            pd = fmaf(acc[i][j], adv[j], pd);
        }
        ps += __shfl_xor(ps, 1, 64); ps += __shfl_xor(ps, 2, 64);
        pd += __shfl_xor(pd, 1, 64); pd += __shfl_xor(pd, 2, 64);
        if ((ct & 3) == 0) {
            int hh = ct >> 2;
            as[gr * 4 + hh] = ps;
            ad[gr * 4 + hh] = pd;
        }
    }
}

// ---------------- per-dst softmax + aggregate ----------------
#define AGG_CAP 256
__global__ __launch_bounds__(128) void k_agg(const unsigned short* __restrict__ h,
                                             const float* __restrict__ as, const float* __restrict__ ad,
                                             const int* __restrict__ rowptr, const int* __restrict__ csrc,
                                             const float* __restrict__ bias,
                                             float* __restrict__ out, int N) {
    __shared__ float w_t[4][AGG_CAP + 1];   // [head][edge], padded row to dodge bank aliasing
    __shared__ int srcs[AGG_CAP];
    __shared__ float mmax_s[4], minv_s[4];
    __shared__ float2 part[64];

    int n = blockIdx.x;
    int tid = threadIdx.x;
    int o0 = rowptr[n], o1 = rowptr[n + 1];
    int deg = o1 - o0;

    float4 adn = *(const float4*)&ad[n * 4];
    float adh[4] = {adn.x, adn.y, adn.z, adn.w};

    if (tid < 64) {
        // wave 0: per-head max then sum over incoming edges
        float mx[4] = {-1e30f, -1e30f, -1e30f, -1e30f};
        for (int i = tid; i < deg; i += 64) {
            int s = csrc[o0 + i];
            float4 a = *(const float4*)&as[s * 4];
            float e0 = lrelu(a.x + adh[0]);
            float e1 = lrelu(a.y + adh[1]);
            float e2 = lrelu(a.z + adh[2]);
            float e3 = lrelu(a.w + adh[3]);
            if (i < AGG_CAP) {
                srcs[i] = s;
                w_t[0][i] = e0; w_t[1][i] = e1; w_t[2][i] = e2; w_t[3][i] = e3;
            }
            mx[0] = fmaxf(mx[0], e0); mx[1] = fmaxf(mx[1], e1);
            mx[2] = fmaxf(mx[2], e2); mx[3] = fmaxf(mx[3], e3);
        }
#pragma unroll
        for (int off = 32; off >= 1; off >>= 1) {
#pragma unroll
            for (int q = 0; q < 4; ++q) mx[q] = fmaxf(mx[q], __shfl_xor(mx[q], off, 64));
        }
        float sm[4] = {0.f, 0.f, 0.f, 0.f};
        for (int i = tid; i < deg; i += 64) {
            float e[4];
            if (i < AGG_CAP) {
                e[0] = w_t[0][i]; e[1] = w_t[1][i]; e[2] = w_t[2][i]; e[3] = w_t[3][i];
            } else {
                int s = csrc[o0 + i];
                float4 a = *(const float4*)&as[s * 4];
                e[0] = lrelu(a.x + adh[0]); e[1] = lrelu(a.y + adh[1]);
                e[2] = lrelu(a.z + adh[2]); e[3] = lrelu(a.w + adh[3]);
            }
#pragma unroll
            for (int q = 0; q < 4; ++q) {
                float ex = expf(e[q] - mx[q]);
                sm[q] += ex;
                if (i < AGG_CAP) w_t[q][i] = ex;
            }
        }
#pragma unroll
        for (int off = 32; off >= 1; off >>= 1) {
#pragma unroll
            for (int q = 0; q < 4; ++q) sm[q] += __shfl_xor(sm[q], off, 64);
        }
        if (tid == 0) {
#pragma unroll
            for (int q = 0; q < 4; ++q) {
                mmax_s[q] = mx[q];
                minv_s[q] = 1.f / (sm[q] + 1e-16f);
            }
        }
    }
    __syncthreads();

    // phase 2: two waves process even/odd edges; each lane owns dims 2c,2c+1
    int g = tid >> 6;            // wave id
    int c = tid & 63;            // lane
    int head = c >> 4;           // dims 2c,2c+1 share head (2c)>>5
    const unsigned* hp = (const unsigned*)h;   // bf16x2 words, 64 per row
    float2 acc = make_float2(0.f, 0.f);
    float mxh = mmax_s[head];
    float adhh = adh[head];
    for (int i = g; i < deg; i += 2) {
        int s; float w;
        if (i < AGG_CAP) {
            s = srcs[i];
            w = w_t[head][i];
        } else {
            s = csrc[o0 + i];
            float e = lrelu(as[s * 4 + head] + adhh);
            w = expf(e - mxh);
        }
        unsigned u = hp[(unsigned)s * 64u + (unsigned)c];
        acc.x = fmaf(w, bflo(u), acc.x);
        acc.y = fmaf(w, bfhi(u), acc.y);
    }
    if (g == 1) part[c] = acc;
    __syncthreads();
    if (g == 0) {
        float2 o = part[c];
        acc.x += o.x; acc.y += o.y;
        float inv = minv_s[head];
        int d0 = c * 2;
        float r0 = acc.x * inv + bias[d0];
        float r1 = acc.y * inv + bias[d0 + 1];
        r0 = r0 > 0.f ? r0 : expf(r0) - 1.f;
        r1 = r1 > 0.f ? r1 : expf(r1) - 1.f;
        *(float2*)&out[(size_t)n * 128 + d0] = make_float2(r0, r1);
    }
}

// ---------------- launch ----------------
extern "C" void kernel_launch(void* const* d_in, const int* in_sizes, int n_in,
                              void* d_out, int out_size, void* d_ws, size_t ws_size,
                              hipStream_t stream) {
    const float* x     = (const float*)d_in[0];
    const int*   ei    = (const int*)d_in[1];     // int32 [2][E] flat
    const float* W     = (const float*)d_in[2];
    const float* att_s = (const float*)d_in[3];
    const float* att_d = (const float*)d_in[4];
    const float* bias  = (const float*)d_in[5];
    float* out = (float*)d_out;

    int N = in_sizes[0] / 128;
    int E = in_sizes[1] / 2;
    int total = E + N;

    auto align256 = [](size_t v) { return (v + 255) & ~(size_t)255; };
    char* wsp = (char*)d_ws;
    size_t off = 0;
    auto alloc = [&](size_t bytes) {
        char* p = wsp + off;
        off += align256(bytes);
        return p;
    };
    unsigned short* h = (unsigned short*)alloc((size_t)N * 128 * 2);   // bf16 h
    float* as     = (float*)alloc((size_t)N * 16);
    float* ad     = (float*)alloc((size_t)N * 16);
    int*   deg    = (int*)alloc((size_t)N * 4);
    int*   excl   = (int*)alloc((size_t)N * 4);
    int*   bsum   = (int*)alloc(4096);
    int*   rowptr = (int*)alloc(((size_t)N + 1) * 4);
    int*   cursor = (int*)alloc((size_t)N * 4);
    int*   csrc   = (int*)alloc((size_t)total * 4);
    (void)ws_size;

    int nbScan = (N + 1023) / 1024;
    int nbEdge = (total + 255) / 256;

    k_zero<<<(N + 255) / 256, 256, 0, stream>>>(deg, N);
    k_hist<<<nbEdge, 256, 0, stream>>>(ei, E, N, deg);
    k_scan1<<<nbScan, 1024, 0, stream>>>(deg, N, excl, bsum);
    k_scan2<<<1, 1024, 0, stream>>>(bsum, nbScan);
    k_scan3<<<(N + 255) / 256, 256, 0, stream>>>(excl, bsum, N, total, rowptr, cursor);
    k_fill<<<nbEdge, 256, 0, stream>>>(ei, E, N, cursor, csrc, total);

    k_gemm<<<(N + 63) / 64, 256, 0, stream>>>(x, W, h, att_s, att_d, as, ad, N);
    k_agg<<<N, 128, 0, stream>>>(h, as, ad, rowptr, csrc, bias, out, N);
}